// Round 1
// baseline (696.332 us; speedup 1.0000x reference)
//
#include <hip/hip_runtime.h>
#include <math.h>

#define NU 100000
#define NI 50000
#define DU 256
#define DI 256
#define EE 128
#define BB 8192
#define TT 24

__global__ void owner_kernel(const int* __restrict__ nodes, int* __restrict__ owner) {
    int b = blockIdx.x * blockDim.x + threadIdx.x;
    if (b < BB) atomicMax(&owner[nodes[b]], b);
}

__global__ __launch_bounds__(256, 2)
void fused_agg_kernel(const int* __restrict__ nodes,
                      const int* __restrict__ neigh_idx,
                      const float* __restrict__ u_weight,
                      const float* __restrict__ i_weight,
                      const float* __restrict__ uW, const float* __restrict__ ub,
                      const float* __restrict__ iW, const float* __restrict__ ib,
                      const float* __restrict__ aW1, const float* __restrict__ ab1,
                      const float* __restrict__ aW2, const float* __restrict__ ab2,
                      const float* __restrict__ aW3, const float* __restrict__ ab3,
                      const int* __restrict__ owner,
                      float* __restrict__ out_nf,     // [B,E]
                      float* __restrict__ out_embed)  // [NU,E]
{
    __shared__ float s_urow[DU];           // 1 KB
    __shared__ float s_irows[TT][DI];      // 24 KB
    __shared__ float s_nf[EE];
    __shared__ float s_np[EE];
    __shared__ float s_neigh[TT][EE];      // 12 KB
    __shared__ float s_h1[TT][EE];         // 12 KB
    __shared__ float s_h2[TT][EE];         // 12 KB
    __shared__ float s_red[256];
    __shared__ float s_att[TT];
    __shared__ int   s_nidx[TT];

    const int b   = blockIdx.x;
    const int tid = threadIdx.x;
    const int e   = tid & (EE - 1);
    const int h   = tid >> 7;              // 0 or 1
    const int node = nodes[b];

    // ---- stage u-row and neighbor indices ----
    s_urow[tid] = u_weight[(size_t)node * DU + tid];
    if (tid < TT) s_nidx[tid] = neigh_idx[b * TT + tid];
    __syncthreads();

    // ---- stage 24 i-rows (each iteration loads one contiguous 1KB row) ----
    for (int i = tid; i < TT * DI; i += 256) {
        int t = i >> 8;       // DI == 256
        int k = i & 255;
        s_irows[t][k] = i_weight[(size_t)s_nidx[t] * DI + k];
    }

    // ---- nodes_fea = u_row @ uW + ub  (split K over h) ----
    {
        float acc = 0.f;
        const float* w = uW + (size_t)(h * 128) * EE + e;
        #pragma unroll 4
        for (int k = 0; k < 128; ++k)
            acc += s_urow[h * 128 + k] * w[(size_t)k * EE];
        s_red[tid] = acc;
    }
    __syncthreads();   // also guarantees s_irows staging complete
    if (h == 0) s_nf[e] = s_red[e] + s_red[e + 128] + ub[e];
    __syncthreads();

    // ---- nodepart = nodes_fea @ aW1[E:2E,:] + ab1 ----
    {
        float acc = 0.f;
        const float* w = aW1 + (size_t)(EE + h * 64) * EE + e;
        #pragma unroll 4
        for (int k = 0; k < 64; ++k)
            acc += s_nf[h * 64 + k] * w[(size_t)k * EE];
        s_red[tid] = acc;
    }
    __syncthreads();
    if (h == 0) s_np[e] = s_red[e] + s_red[e + 128] + ab1[e];
    __syncthreads();

    // ---- neighs[t][e] = i_rows[t] @ iW + ib ; thread owns 12 t's ----
    {
        float acc[12];
        #pragma unroll
        for (int j = 0; j < 12; ++j) acc[j] = 0.f;
        const float* w = iW + e;
        #pragma unroll 4
        for (int k = 0; k < DI; ++k) {
            float wv = w[(size_t)k * EE];
            #pragma unroll
            for (int j = 0; j < 12; ++j)
                acc[j] += s_irows[h * 12 + j][k] * wv;
        }
        float bias = ib[e];
        #pragma unroll
        for (int j = 0; j < 12; ++j)
            s_neigh[h * 12 + j][e] = acc[j] + bias;
    }
    __syncthreads();

    // ---- h1[t][e] = relu(neighs[t] @ aW1[0:E,:] + nodepart[e]) ----
    {
        float acc[12];
        #pragma unroll
        for (int j = 0; j < 12; ++j) acc[j] = 0.f;
        const float* w = aW1 + e;
        #pragma unroll 4
        for (int k = 0; k < EE; ++k) {
            float wv = w[(size_t)k * EE];
            #pragma unroll
            for (int j = 0; j < 12; ++j)
                acc[j] += s_neigh[h * 12 + j][k] * wv;
        }
        float np = s_np[e];
        #pragma unroll
        for (int j = 0; j < 12; ++j)
            s_h1[h * 12 + j][e] = fmaxf(acc[j] + np, 0.f);
    }
    __syncthreads();

    // ---- h2[t][e] = relu(h1[t] @ aW2 + ab2) ----
    {
        float acc[12];
        #pragma unroll
        for (int j = 0; j < 12; ++j) acc[j] = 0.f;
        const float* w = aW2 + e;
        #pragma unroll 4
        for (int k = 0; k < EE; ++k) {
            float wv = w[(size_t)k * EE];
            #pragma unroll
            for (int j = 0; j < 12; ++j)
                acc[j] += s_h1[h * 12 + j][k] * wv;
        }
        float bias = ab2[e];
        #pragma unroll
        for (int j = 0; j < 12; ++j)
            s_h2[h * 12 + j][e] = fmaxf(acc[j] + bias, 0.f);
    }
    __syncthreads();

    // ---- logits[t] = h2[t] @ aW3 + ab3 ; 8 lanes per t ----
    if (tid < TT * 8) {
        int t = tid >> 3;
        int sub = tid & 7;
        float acc = 0.f;
        #pragma unroll
        for (int m = 0; m < 16; ++m)
            acc += s_h2[t][sub + 8 * m] * aW3[sub + 8 * m];
        acc += __shfl_down(acc, 4, 8);
        acc += __shfl_down(acc, 2, 8);
        acc += __shfl_down(acc, 1, 8);
        if (sub == 0) s_red[t] = acc + ab3[0];
    }
    __syncthreads();

    // ---- softmax over T in wave 0 ----
    if (tid < 64) {
        float v = (tid < TT) ? s_red[tid] : -INFINITY;
        float mx = v;
        #pragma unroll
        for (int d = 32; d > 0; d >>= 1)
            mx = fmaxf(mx, __shfl_xor(mx, d, 64));
        float p = (tid < TT) ? expf(v - mx) : 0.f;
        float sm = p;
        #pragma unroll
        for (int d = 32; d > 0; d >>= 1)
            sm += __shfl_xor(sm, d, 64);
        if (tid < TT) s_att[tid] = p / sm;
    }
    __syncthreads();

    // ---- agg[e] = sum_t att[t] * neighs[t][e] ; write outputs ----
    {
        float acc = 0.f;
        #pragma unroll
        for (int j = 0; j < 12; ++j)
            acc += s_att[h * 12 + j] * s_neigh[h * 12 + j][e];
        s_red[tid] = acc;
    }
    __syncthreads();
    if (h == 0) {
        float agg = s_red[e] + s_red[e + 128];
        out_nf[(size_t)b * EE + e] = s_nf[e];
        if (owner[node] == b)
            out_embed[(size_t)node * EE + e] = agg;
    }
}

extern "C" void kernel_launch(void* const* d_in, const int* in_sizes, int n_in,
                              void* d_out, int out_size, void* d_ws, size_t ws_size,
                              hipStream_t stream) {
    const int*   nodes     = (const int*)d_in[0];
    const int*   neigh_idx = (const int*)d_in[1];
    const float* u_weight  = (const float*)d_in[2];
    const float* i_weight  = (const float*)d_in[3];
    const float* uW  = (const float*)d_in[4];
    const float* ub  = (const float*)d_in[5];
    const float* iW  = (const float*)d_in[6];
    const float* ib  = (const float*)d_in[7];
    const float* aW1 = (const float*)d_in[8];
    const float* ab1 = (const float*)d_in[9];
    const float* aW2 = (const float*)d_in[10];
    const float* ab2 = (const float*)d_in[11];
    const float* aW3 = (const float*)d_in[12];
    const float* ab3 = (const float*)d_in[13];

    float* out_nf    = (float*)d_out;
    float* out_embed = out_nf + (size_t)BB * EE;
    int*   owner     = (int*)d_ws;

    // zero the scatter target (harness poisons, doesn't re-poison between replays)
    hipMemsetAsync(out_embed, 0, (size_t)NU * EE * sizeof(float), stream);
    // owner[] = -1, then last-occurrence-wins resolution
    hipMemsetAsync(owner, 0xFF, (size_t)NU * sizeof(int), stream);
    owner_kernel<<<(BB + 255) / 256, 256, 0, stream>>>(nodes, owner);

    fused_agg_kernel<<<BB, 256, 0, stream>>>(
        nodes, neigh_idx, u_weight, i_weight,
        uW, ub, iW, ib, aW1, ab1, aW2, ab2, aW3, ab3,
        owner, out_nf, out_embed);
}

// Round 2
// 170.564 us; speedup vs baseline: 4.0825x; 4.0825x over previous
//
#include <hip/hip_runtime.h>
#include <math.h>

#define NU 100000
#define NI 50000
#define DK 256      // DU == DI
#define EN 128      // E
#define BB 8192
#define TT 24
#define GG 2        // batch rows per block
#define MM 48       // GG*TT rows of neighbors per block

typedef short short8 __attribute__((ext_vector_type(8)));
typedef float f32x4  __attribute__((ext_vector_type(4)));

// packed-weight layout in d_ws (element offsets, bf16 shorts), all [N][K] k-contiguous
#define OFF_IWT   0        // 128x256
#define OFF_UWT   32768    // 128x256
#define OFF_AW1UT 65536    // 128x128 (aW1 rows 0..127   -> neigh part)
#define OFF_AW1LT 81920    // 128x128 (aW1 rows 128..255 -> node part)
#define OFF_AW2T  98304    // 128x128
#define WPACK_SHORTS 114688
#define OWNER_BYTE_OFF (WPACK_SHORTS * 2)

__device__ __forceinline__ unsigned short f2b(float x) {
    unsigned int u = __float_as_uint(x);
    u = (u + 0x7FFFu + ((u >> 16) & 1u)) >> 16;   // RNE, finite inputs
    return (unsigned short)u;
}
__device__ __forceinline__ float b2f(unsigned short v) {
    return __uint_as_float(((unsigned int)v) << 16);
}

__global__ void owner_kernel(const int* __restrict__ nodes, int* __restrict__ owner) {
    int b = blockIdx.x * blockDim.x + threadIdx.x;
    if (b < BB) atomicMax(&owner[nodes[b]], b);
}

__global__ void pack_weights(const float* __restrict__ uW, const float* __restrict__ iW,
                             const float* __restrict__ aW1, const float* __restrict__ aW2,
                             short* __restrict__ wp) {
    int i = blockIdx.x * 256 + threadIdx.x;
    if (i >= WPACK_SHORTS) return;
    float v;
    if (i < 32768)      { int j = i;         int n = j >> 8, k = j & 255; v = iW[k * EN + n]; }
    else if (i < 65536) { int j = i - 32768; int n = j >> 8, k = j & 255; v = uW[k * EN + n]; }
    else if (i < 81920) { int j = i - 65536; int n = j >> 7, k = j & 127; v = aW1[k * EN + n]; }
    else if (i < 98304) { int j = i - 81920; int n = j >> 7, k = j & 127; v = aW1[(128 + k) * EN + n]; }
    else                { int j = i - 98304; int n = j >> 7, k = j & 127; v = aW2[k * EN + n]; }
    wp[i] = (short)f2b(v);
}

#define MFMA(a, b, c) __builtin_amdgcn_mfma_f32_16x16x32_bf16((a), (b), (c), 0, 0, 0)

__global__ __launch_bounds__(256, 2)
void fused_mfma(const int* __restrict__ nodes, const int* __restrict__ neigh_idx,
                const float* __restrict__ u_weight, const float* __restrict__ i_weight,
                const float* __restrict__ ub, const float* __restrict__ ib,
                const float* __restrict__ ab1, const float* __restrict__ ab2,
                const float* __restrict__ aW3, const float* __restrict__ ab3,
                const short* __restrict__ wp, const int* __restrict__ owner,
                float* __restrict__ out_nf, float* __restrict__ out_embed)
{
    // row strides padded to 264 elems (528 B) / 136 elems (272 B): 528%128==16,
    // 272%128==16 -> rows rotate banks by 4, b128 A-frag reads are balanced.
    __shared__ short sA[64 * 264];     // 33792 B: rows 0..47 i-rows, 48..49 u-rows; later h2 overlay
    __shared__ short sNg[MM * 136];    // 13056 B: neighs bf16
    __shared__ short sH1[MM * 136];    // 13056 B
    __shared__ short sNfb[16 * 136];   //  4352 B: nodes_fea bf16 (rows 0..1 real)
    __shared__ float sNp[2 * EN];      // nodepart (incl. ab1)
    __shared__ float sW3[EN];
    __shared__ float sLog[MM];
    __shared__ float sAtt[MM];
    __shared__ int   sIdx[MM];
    __shared__ int   sNode[GG];

    const int tid = threadIdx.x;
    const int b0  = blockIdx.x * GG;
    const int l   = tid & 63;
    const int lr  = l & 15;            // row (A) / col (B,C) within 16-tile
    const int lq  = l >> 4;            // k-group (A,B) / row-group (C)
    const int n0  = (tid >> 6) * 32;   // wave's 32-col slice

    if (tid < MM) sIdx[tid]  = neigh_idx[b0 * TT + tid];
    if (tid < GG) sNode[tid] = nodes[b0 + tid];
    if (tid < EN) sW3[tid]   = aW3[tid];
    __syncthreads();

    // ---- stage 50 rows x 256 k as bf16 (coalesced fp32 reads, b128 LDS writes) ----
    for (int task = tid; task < 50 * 32; task += 256) {
        int row = task >> 5, c = task & 31;
        const float* src = (row < MM)
            ? (i_weight + (size_t)sIdx[row] * DK + c * 8)
            : (u_weight + (size_t)sNode[row - MM] * DK + c * 8);
        float4 f0 = *(const float4*)src;
        float4 f1 = *(const float4*)(src + 4);
        short8 o;
        o[0] = f2b(f0.x); o[1] = f2b(f0.y); o[2] = f2b(f0.z); o[3] = f2b(f0.w);
        o[4] = f2b(f1.x); o[5] = f2b(f1.y); o[6] = f2b(f1.z); o[7] = f2b(f1.w);
        *reinterpret_cast<short8*>(reinterpret_cast<char*>(sA) + row * 528 + c * 16) = o;
    }
    __syncthreads();

    const int kA  = lq * 8;
    const int nc0 = n0 + lr, nc1 = n0 + 16 + lr;
    const short* iWt   = wp + OFF_IWT;
    const short* uWt   = wp + OFF_UWT;
    const short* aW1Ut = wp + OFF_AW1UT;
    const short* aW1Lt = wp + OFF_AW1LT;
    const short* aW2t  = wp + OFF_AW2T;

#define LDA528(row, k) (*reinterpret_cast<const short8*>(reinterpret_cast<const char*>(sA)  + (row) * 528 + (k) * 2))
#define LD272(buf, row, k) (*reinterpret_cast<const short8*>(reinterpret_cast<const char*>(buf) + (row) * 272 + (k) * 2))

    // ---- nodes_fea GEMM: A rows 48..63 (2 real), B = uWt, K=256 ----
    f32x4 accn[2];
    accn[0] = {0.f, 0.f, 0.f, 0.f}; accn[1] = {0.f, 0.f, 0.f, 0.f};
    #pragma unroll
    for (int ks = 0; ks < 8; ++ks) {
        int k = ks * 32 + kA;
        short8 a  = LDA528(48 + lr, k);
        short8 w0 = *reinterpret_cast<const short8*>(uWt + nc0 * DK + k);
        short8 w1 = *reinterpret_cast<const short8*>(uWt + nc1 * DK + k);
        accn[0] = MFMA(a, w0, accn[0]);
        accn[1] = MFMA(a, w1, accn[1]);
    }
    if (lq == 0) {   // C rows 0..1 = the 2 real b-rows
        #pragma unroll
        for (int nt = 0; nt < 2; ++nt) {
            int n = nt ? nc1 : nc0;
            #pragma unroll
            for (int g = 0; g < GG; ++g) {
                float v = accn[nt][g] + ub[n];
                out_nf[(size_t)(b0 + g) * EN + n] = v;
                *reinterpret_cast<short*>(reinterpret_cast<char*>(sNfb) + g * 272 + n * 2) = (short)f2b(v);
            }
        }
    }

    // ---- neighs GEMM: A rows 0..47, B = iWt, K=256 ----
    f32x4 acc[3][2];
    #pragma unroll
    for (int m = 0; m < 3; ++m) { acc[m][0] = {0.f,0.f,0.f,0.f}; acc[m][1] = {0.f,0.f,0.f,0.f}; }
    #pragma unroll
    for (int ks = 0; ks < 8; ++ks) {
        int k = ks * 32 + kA;
        short8 a0 = LDA528(lr, k);
        short8 a1 = LDA528(16 + lr, k);
        short8 a2 = LDA528(32 + lr, k);
        short8 w0 = *reinterpret_cast<const short8*>(iWt + nc0 * DK + k);
        short8 w1 = *reinterpret_cast<const short8*>(iWt + nc1 * DK + k);
        acc[0][0] = MFMA(a0, w0, acc[0][0]); acc[0][1] = MFMA(a0, w1, acc[0][1]);
        acc[1][0] = MFMA(a1, w0, acc[1][0]); acc[1][1] = MFMA(a1, w1, acc[1][1]);
        acc[2][0] = MFMA(a2, w0, acc[2][0]); acc[2][1] = MFMA(a2, w1, acc[2][1]);
    }
    {
        float ibv0 = ib[nc0], ibv1 = ib[nc1];
        #pragma unroll
        for (int m = 0; m < 3; ++m)
            #pragma unroll
            for (int nt = 0; nt < 2; ++nt) {
                int n = nt ? nc1 : nc0;
                float bv = nt ? ibv1 : ibv0;
                #pragma unroll
                for (int r = 0; r < 4; ++r) {
                    int row = m * 16 + lq * 4 + r;
                    float v = acc[m][nt][r] + bv;
                    *reinterpret_cast<short*>(reinterpret_cast<char*>(sNg) + row * 272 + n * 2) = (short)f2b(v);
                }
            }
    }
    __syncthreads();

    // ---- nodepart GEMM: A = sNfb rows 0..15 (2 real), B = aW1Lt, K=128 ----
    f32x4 accp[2];
    accp[0] = {0.f,0.f,0.f,0.f}; accp[1] = {0.f,0.f,0.f,0.f};
    #pragma unroll
    for (int ks = 0; ks < 4; ++ks) {
        int k = ks * 32 + kA;
        short8 a  = LD272(sNfb, lr, k);
        short8 w0 = *reinterpret_cast<const short8*>(aW1Lt + nc0 * EN + k);
        short8 w1 = *reinterpret_cast<const short8*>(aW1Lt + nc1 * EN + k);
        accp[0] = MFMA(a, w0, accp[0]);
        accp[1] = MFMA(a, w1, accp[1]);
    }
    if (lq == 0) {
        #pragma unroll
        for (int nt = 0; nt < 2; ++nt) {
            int n = nt ? nc1 : nc0;
            #pragma unroll
            for (int g = 0; g < GG; ++g)
                sNp[g * EN + n] = accp[nt][g] + ab1[n];
        }
    }

    // ---- h1 GEMM: A = sNg (bf16 neighs), B = aW1Ut, K=128; + nodepart, relu ----
    f32x4 ac1[3][2];
    #pragma unroll
    for (int m = 0; m < 3; ++m) { ac1[m][0] = {0.f,0.f,0.f,0.f}; ac1[m][1] = {0.f,0.f,0.f,0.f}; }
    #pragma unroll
    for (int ks = 0; ks < 4; ++ks) {
        int k = ks * 32 + kA;
        short8 a0 = LD272(sNg, lr, k);
        short8 a1 = LD272(sNg, 16 + lr, k);
        short8 a2 = LD272(sNg, 32 + lr, k);
        short8 w0 = *reinterpret_cast<const short8*>(aW1Ut + nc0 * EN + k);
        short8 w1 = *reinterpret_cast<const short8*>(aW1Ut + nc1 * EN + k);
        ac1[0][0] = MFMA(a0, w0, ac1[0][0]); ac1[0][1] = MFMA(a0, w1, ac1[0][1]);
        ac1[1][0] = MFMA(a1, w0, ac1[1][0]); ac1[1][1] = MFMA(a1, w1, ac1[1][1]);
        ac1[2][0] = MFMA(a2, w0, ac1[2][0]); ac1[2][1] = MFMA(a2, w1, ac1[2][1]);
    }
    #pragma unroll
    for (int m = 0; m < 3; ++m)
        #pragma unroll
        for (int nt = 0; nt < 2; ++nt) {
            int n = nt ? nc1 : nc0;
            #pragma unroll
            for (int r = 0; r < 4; ++r) {
                int row = m * 16 + lq * 4 + r;
                int g = (row >= TT) ? 1 : 0;
                float v = ac1[m][nt][r] + sNp[g * EN + n];
                v = fmaxf(v, 0.f);
                *reinterpret_cast<short*>(reinterpret_cast<char*>(sH1) + row * 272 + n * 2) = (short)f2b(v);
            }
        }
    __syncthreads();

    // ---- h2 GEMM: A = sH1, B = aW2t, K=128; + ab2, relu -> overlay into sA ----
    char* sH2 = reinterpret_cast<char*>(sA);
    f32x4 ac2[3][2];
    #pragma unroll
    for (int m = 0; m < 3; ++m) { ac2[m][0] = {0.f,0.f,0.f,0.f}; ac2[m][1] = {0.f,0.f,0.f,0.f}; }
    #pragma unroll
    for (int ks = 0; ks < 4; ++ks) {
        int k = ks * 32 + kA;
        short8 a0 = LD272(sH1, lr, k);
        short8 a1 = LD272(sH1, 16 + lr, k);
        short8 a2 = LD272(sH1, 32 + lr, k);
        short8 w0 = *reinterpret_cast<const short8*>(aW2t + nc0 * EN + k);
        short8 w1 = *reinterpret_cast<const short8*>(aW2t + nc1 * EN + k);
        ac2[0][0] = MFMA(a0, w0, ac2[0][0]); ac2[0][1] = MFMA(a0, w1, ac2[0][1]);
        ac2[1][0] = MFMA(a1, w0, ac2[1][0]); ac2[1][1] = MFMA(a1, w1, ac2[1][1]);
        ac2[2][0] = MFMA(a2, w0, ac2[2][0]); ac2[2][1] = MFMA(a2, w1, ac2[2][1]);
    }
    {
        float a2v0 = ab2[nc0], a2v1 = ab2[nc1];
        #pragma unroll
        for (int m = 0; m < 3; ++m)
            #pragma unroll
            for (int nt = 0; nt < 2; ++nt) {
                int n = nt ? nc1 : nc0;
                float bv = nt ? a2v1 : a2v0;
                #pragma unroll
                for (int r = 0; r < 4; ++r) {
                    int row = m * 16 + lq * 4 + r;
                    float v = fmaxf(ac2[m][nt][r] + bv, 0.f);
                    *reinterpret_cast<short*>(sH2 + row * 272 + n * 2) = (short)f2b(v);
                }
            }
    }
    __syncthreads();

    // ---- logits: t-dot over 128 cols of h2, 4 lanes per t ----
    if (tid < MM * 4) {
        int t = tid >> 2, sub = tid & 3;
        float accl = 0.f;
        #pragma unroll
        for (int j = 0; j < 4; ++j) {
            short8 hv = *reinterpret_cast<const short8*>(sH2 + t * 272 + (sub * 32 + j * 8) * 2);
            #pragma unroll
            for (int m2 = 0; m2 < 8; ++m2)
                accl += b2f((unsigned short)hv[m2]) * sW3[sub * 32 + j * 8 + m2];
        }
        accl += __shfl_down(accl, 2, 4);
        accl += __shfl_down(accl, 1, 4);
        if (sub == 0) sLog[t] = accl + ab3[0];
    }
    __syncthreads();

    // ---- softmax over T=24 per g (2 groups in wave 0) ----
    if (tid < 64) {
        int g = tid >> 5, tt = tid & 31;
        float v = (tt < TT) ? sLog[g * TT + tt] : -1e30f;
        float mx = v;
        #pragma unroll
        for (int d = 16; d > 0; d >>= 1) mx = fmaxf(mx, __shfl_xor(mx, d, 32));
        float p = (tt < TT) ? __expf(v - mx) : 0.f;
        float s = p;
        #pragma unroll
        for (int d = 16; d > 0; d >>= 1) s += __shfl_xor(s, d, 32);
        if (tt < TT) sAtt[g * TT + tt] = p / s;
    }
    __syncthreads();

    // ---- agg + scatter ----
    {
        int g = tid >> 7, e = tid & 127;
        float a = 0.f;
        #pragma unroll
        for (int t = 0; t < TT; ++t) {
            unsigned short nv = *reinterpret_cast<const unsigned short*>(
                reinterpret_cast<const char*>(sNg) + (g * TT + t) * 272 + e * 2);
            a += sAtt[g * TT + t] * b2f(nv);
        }
        int node = sNode[g];
        if (owner[node] == b0 + g)
            out_embed[(size_t)node * EN + e] = a;
    }
}

extern "C" void kernel_launch(void* const* d_in, const int* in_sizes, int n_in,
                              void* d_out, int out_size, void* d_ws, size_t ws_size,
                              hipStream_t stream) {
    const int*   nodes     = (const int*)d_in[0];
    const int*   neigh_idx = (const int*)d_in[1];
    const float* u_weight  = (const float*)d_in[2];
    const float* i_weight  = (const float*)d_in[3];
    const float* uW  = (const float*)d_in[4];
    const float* ub  = (const float*)d_in[5];
    const float* iW  = (const float*)d_in[6];
    const float* ib  = (const float*)d_in[7];
    const float* aW1 = (const float*)d_in[8];
    const float* ab1 = (const float*)d_in[9];
    const float* aW2 = (const float*)d_in[10];
    const float* ab2 = (const float*)d_in[11];
    const float* aW3 = (const float*)d_in[12];
    const float* ab3 = (const float*)d_in[13];

    float* out_nf    = (float*)d_out;
    float* out_embed = out_nf + (size_t)BB * EN;
    short* wpack     = (short*)d_ws;
    int*   owner     = (int*)((char*)d_ws + OWNER_BYTE_OFF);

    hipMemsetAsync(out_embed, 0, (size_t)NU * EN * sizeof(float), stream);
    hipMemsetAsync(owner, 0xFF, (size_t)NU * sizeof(int), stream);
    owner_kernel<<<(BB + 255) / 256, 256, 0, stream>>>(nodes, owner);
    pack_weights<<<(WPACK_SHORTS + 255) / 256, 256, 0, stream>>>(uW, iW, aW1, aW2, wpack);

    fused_mfma<<<BB / GG, 256, 0, stream>>>(
        nodes, neigh_idx, u_weight, i_weight,
        ub, ib, ab1, ab2, aW3, ab3,
        wpack, owner, out_nf, out_embed);
}

// Round 3
// 100.234 us; speedup vs baseline: 6.9471x; 1.7017x over previous
//
#include <hip/hip_runtime.h>
#include <math.h>

#define NU 100000
#define NI 50000
#define DK 256      // DU == DI
#define EN 128      // E
#define BB 8192
#define TT 24

typedef short short8 __attribute__((ext_vector_type(8)));
typedef float f32x4  __attribute__((ext_vector_type(4)));

// ---- d_ws layout (bytes) ----
#define WPACK_SHORTS 114688
#define WP_OFF     0
#define OWNER_OFF  229376                 // 100000 ints
#define NTAB_OFF   629376                 // 50000*128 bf16 = 12.8 MB
#define NPART_OFF  13429376               // 8192*128 f32  = 4 MB

// wpack element offsets (bf16 shorts, all [N][K] k-contiguous)
#define OFF_IWT   0        // 128x256
#define OFF_UWT   32768    // 128x256
#define OFF_AW1UT 65536    // 128x128 (aW1 rows 0..127   -> neigh part)
#define OFF_AW1LT 81920    // 128x128 (aW1 rows 128..255 -> node part)
#define OFF_AW2T  98304    // 128x128

__device__ __forceinline__ unsigned short f2b(float x) {
    unsigned int u = __float_as_uint(x);
    u = (u + 0x7FFFu + ((u >> 16) & 1u)) >> 16;   // RNE, finite inputs
    return (unsigned short)u;
}
__device__ __forceinline__ float b2f(unsigned short v) {
    return __uint_as_float(((unsigned int)v) << 16);
}

#define MFMA(a, b, c) __builtin_amdgcn_mfma_f32_16x16x32_bf16((a), (b), (c), 0, 0, 0)
#define LDROW(buf, stride, row, k) \
    (*reinterpret_cast<const short8*>(reinterpret_cast<const char*>(buf) + (row) * (stride) + (k) * 2))

__global__ void owner_kernel(const int* __restrict__ nodes, int* __restrict__ owner) {
    int b = blockIdx.x * blockDim.x + threadIdx.x;
    if (b < BB) atomicMax(&owner[nodes[b]], b);
}

__global__ void pack_weights(const float* __restrict__ uW, const float* __restrict__ iW,
                             const float* __restrict__ aW1, const float* __restrict__ aW2,
                             short* __restrict__ wp) {
    int i = blockIdx.x * 256 + threadIdx.x;
    if (i >= WPACK_SHORTS) return;
    float v;
    if (i < 32768)      { int j = i;         int n = j >> 8, k = j & 255; v = iW[k * EN + n]; }
    else if (i < 65536) { int j = i - 32768; int n = j >> 8, k = j & 255; v = uW[k * EN + n]; }
    else if (i < 81920) { int j = i - 65536; int n = j >> 7, k = j & 127; v = aW1[k * EN + n]; }
    else if (i < 98304) { int j = i - 81920; int n = j >> 7, k = j & 127; v = aW1[(128 + k) * EN + n]; }
    else                { int j = i - 98304; int n = j >> 7, k = j & 127; v = aW2[k * EN + n]; }
    wp[i] = (short)f2b(v);
}

// ---- K3: neighs_all[NI][128] bf16 = i_weight @ iW + ib (dense, coalesced) ----
__global__ __launch_bounds__(256, 2)
void neighs_all_kernel(const float* __restrict__ i_weight, const float* __restrict__ ib,
                       const short* __restrict__ wp, short* __restrict__ ntab)
{
    __shared__ __align__(16) short sA[64 * 264];   // 33792 B, 528B row stride
    __shared__ __align__(16) short sO[64 * 132];   // 16896 B, 264B row stride
    const int tid = threadIdx.x;
    const int r0  = blockIdx.x * 64;
    const int nrows = (NI - r0 < 64) ? (NI - r0) : 64;

    for (int task = tid; task < 64 * 32; task += 256) {
        int row = task >> 5, c = task & 31;
        if (row < nrows) {
            const float* src = i_weight + (size_t)(r0 + row) * DK + c * 8;
            float4 f0 = *(const float4*)src;
            float4 f1 = *(const float4*)(src + 4);
            short8 o;
            o[0]=f2b(f0.x); o[1]=f2b(f0.y); o[2]=f2b(f0.z); o[3]=f2b(f0.w);
            o[4]=f2b(f1.x); o[5]=f2b(f1.y); o[6]=f2b(f1.z); o[7]=f2b(f1.w);
            *reinterpret_cast<short8*>(reinterpret_cast<char*>(sA) + row * 528 + c * 16) = o;
        }
    }
    __syncthreads();

    const int l = tid & 63, lr = l & 15, lq = l >> 4, n0 = (tid >> 6) * 32;
    const int kA = lq * 8, nc0 = n0 + lr, nc1 = n0 + 16 + lr;
    const short* iWt = wp + OFF_IWT;

    f32x4 acc[4][2];
    #pragma unroll
    for (int m = 0; m < 4; ++m) { acc[m][0] = {0.f,0.f,0.f,0.f}; acc[m][1] = {0.f,0.f,0.f,0.f}; }
    #pragma unroll
    for (int ks = 0; ks < 8; ++ks) {
        int k = ks * 32 + kA;
        short8 w0 = *reinterpret_cast<const short8*>(iWt + nc0 * DK + k);
        short8 w1 = *reinterpret_cast<const short8*>(iWt + nc1 * DK + k);
        #pragma unroll
        for (int m = 0; m < 4; ++m) {
            short8 a = LDROW(sA, 528, m * 16 + lr, k);
            acc[m][0] = MFMA(a, w0, acc[m][0]);
            acc[m][1] = MFMA(a, w1, acc[m][1]);
        }
    }
    {
        float ib0 = ib[nc0], ib1 = ib[nc1];
        #pragma unroll
        for (int m = 0; m < 4; ++m)
            #pragma unroll
            for (int nt = 0; nt < 2; ++nt) {
                int n = nt ? nc1 : nc0;
                float bv = nt ? ib1 : ib0;
                #pragma unroll
                for (int r = 0; r < 4; ++r) {
                    int row = m * 16 + lq * 4 + r;
                    *reinterpret_cast<short*>(reinterpret_cast<char*>(sO) + row * 264 + n * 2)
                        = (short)f2b(acc[m][nt][r] + bv);
                }
            }
    }
    __syncthreads();
    for (int g = tid; g < nrows * 16; g += 256) {
        int row = g >> 4, s = g & 15;
        short8 v = *reinterpret_cast<const short8*>(reinterpret_cast<const char*>(sO) + row * 264 + s * 16);
        *reinterpret_cast<short8*>(ntab + (size_t)(r0 + row) * EN + s * 8) = v;
    }
}

// ---- K4: nf = u_weight[nodes] @ uW + ub (write out_nf); npart = nf @ aW1L + ab1 ----
__global__ __launch_bounds__(256, 2)
void nf_npart_kernel(const int* __restrict__ nodes, const float* __restrict__ u_weight,
                     const float* __restrict__ ub, const float* __restrict__ ab1,
                     const short* __restrict__ wp,
                     float* __restrict__ out_nf, float* __restrict__ npart)
{
    __shared__ __align__(16) short sU[64 * 264];   // 33792 B
    __shared__ __align__(16) short sNf[64 * 136];  // 17408 B, 272B stride
    __shared__ int sNd[64];
    const int tid = threadIdx.x;
    const int r0  = blockIdx.x * 64;

    if (tid < 64) sNd[tid] = nodes[r0 + tid];
    __syncthreads();

    for (int task = tid; task < 64 * 32; task += 256) {
        int row = task >> 5, c = task & 31;
        const float* src = u_weight + (size_t)sNd[row] * DK + c * 8;
        float4 f0 = *(const float4*)src;
        float4 f1 = *(const float4*)(src + 4);
        short8 o;
        o[0]=f2b(f0.x); o[1]=f2b(f0.y); o[2]=f2b(f0.z); o[3]=f2b(f0.w);
        o[4]=f2b(f1.x); o[5]=f2b(f1.y); o[6]=f2b(f1.z); o[7]=f2b(f1.w);
        *reinterpret_cast<short8*>(reinterpret_cast<char*>(sU) + row * 528 + c * 16) = o;
    }
    __syncthreads();

    const int l = tid & 63, lr = l & 15, lq = l >> 4, n0 = (tid >> 6) * 32;
    const int kA = lq * 8, nc0 = n0 + lr, nc1 = n0 + 16 + lr;
    const short* uWt   = wp + OFF_UWT;
    const short* aW1Lt = wp + OFF_AW1LT;

    f32x4 acc[4][2];
    #pragma unroll
    for (int m = 0; m < 4; ++m) { acc[m][0] = {0.f,0.f,0.f,0.f}; acc[m][1] = {0.f,0.f,0.f,0.f}; }
    #pragma unroll
    for (int ks = 0; ks < 8; ++ks) {
        int k = ks * 32 + kA;
        short8 w0 = *reinterpret_cast<const short8*>(uWt + nc0 * DK + k);
        short8 w1 = *reinterpret_cast<const short8*>(uWt + nc1 * DK + k);
        #pragma unroll
        for (int m = 0; m < 4; ++m) {
            short8 a = LDROW(sU, 528, m * 16 + lr, k);
            acc[m][0] = MFMA(a, w0, acc[m][0]);
            acc[m][1] = MFMA(a, w1, acc[m][1]);
        }
    }
    {
        float b0v = ub[nc0], b1v = ub[nc1];
        #pragma unroll
        for (int m = 0; m < 4; ++m)
            #pragma unroll
            for (int nt = 0; nt < 2; ++nt) {
                int n = nt ? nc1 : nc0;
                float bv = nt ? b1v : b0v;
                #pragma unroll
                for (int r = 0; r < 4; ++r) {
                    int row = m * 16 + lq * 4 + r;
                    float v = acc[m][nt][r] + bv;
                    out_nf[(size_t)(r0 + row) * EN + n] = v;
                    *reinterpret_cast<short*>(reinterpret_cast<char*>(sNf) + row * 272 + n * 2)
                        = (short)f2b(v);
                }
            }
    }
    __syncthreads();

    f32x4 ap[4][2];
    #pragma unroll
    for (int m = 0; m < 4; ++m) { ap[m][0] = {0.f,0.f,0.f,0.f}; ap[m][1] = {0.f,0.f,0.f,0.f}; }
    #pragma unroll
    for (int ks = 0; ks < 4; ++ks) {
        int k = ks * 32 + kA;
        short8 w0 = *reinterpret_cast<const short8*>(aW1Lt + nc0 * EN + k);
        short8 w1 = *reinterpret_cast<const short8*>(aW1Lt + nc1 * EN + k);
        #pragma unroll
        for (int m = 0; m < 4; ++m) {
            short8 a = LDROW(sNf, 272, m * 16 + lr, k);
            ap[m][0] = MFMA(a, w0, ap[m][0]);
            ap[m][1] = MFMA(a, w1, ap[m][1]);
        }
    }
    {
        float b0v = ab1[nc0], b1v = ab1[nc1];
        #pragma unroll
        for (int m = 0; m < 4; ++m)
            #pragma unroll
            for (int nt = 0; nt < 2; ++nt) {
                int n = nt ? nc1 : nc0;
                float bv = nt ? b1v : b0v;
                #pragma unroll
                for (int r = 0; r < 4; ++r) {
                    int row = m * 16 + lq * 4 + r;
                    npart[(size_t)(r0 + row) * EN + n] = ap[m][nt][r] + bv;
                }
            }
    }
}

// ---- K5: per 2 batch rows: gather neighs -> h1 -> h2 -> logits -> softmax -> agg ----
__global__ __launch_bounds__(256, 4)
void attn_kernel(const int* __restrict__ nodes, const int* __restrict__ neigh_idx,
                 const float* __restrict__ ab2, const float* __restrict__ aW3,
                 const float* __restrict__ ab3, const short* __restrict__ wp,
                 const short* __restrict__ ntab, const float* __restrict__ npart,
                 const int* __restrict__ owner, float* __restrict__ out_embed)
{
    __shared__ __align__(16) short sNg[48 * 136];  // 13056 B, 272B stride
    __shared__ __align__(16) short sH1[48 * 136];  // 13056 B
    __shared__ float sNp[256];
    __shared__ float sW3[EN];
    __shared__ float sLogP[4][48];
    __shared__ float sLog[48];
    __shared__ float sAtt[48];
    __shared__ int   sIdx[48];
    __shared__ int   sNode[2];

    const int tid = threadIdx.x;
    const int b0  = blockIdx.x * 2;

    if (tid < 48) sIdx[tid]  = neigh_idx[b0 * TT + tid];
    if (tid < 2)  sNode[tid] = nodes[b0 + tid];
    if (tid < EN) sW3[tid]   = aW3[tid];
    sNp[tid] = npart[(size_t)b0 * EN + tid];
    __syncthreads();

    // stage 48 neighbor rows (256B bf16 each) from the hot table
    for (int task = tid; task < 48 * 16; task += 256) {
        int row = task >> 4, s = task & 15;
        short8 v = *reinterpret_cast<const short8*>(ntab + (size_t)sIdx[row] * EN + s * 8);
        *reinterpret_cast<short8*>(reinterpret_cast<char*>(sNg) + row * 272 + s * 16) = v;
    }
    __syncthreads();

    const int l = tid & 63, lr = l & 15, lq = l >> 4;
    const int wid = tid >> 6, n0 = wid * 32;
    const int kA = lq * 8, nc0 = n0 + lr, nc1 = n0 + 16 + lr;
    const short* aW1Ut = wp + OFF_AW1UT;
    const short* aW2t  = wp + OFF_AW2T;

    // h1 = relu(neighs @ aW1U + npart)
    f32x4 a1[3][2];
    #pragma unroll
    for (int m = 0; m < 3; ++m) { a1[m][0] = {0.f,0.f,0.f,0.f}; a1[m][1] = {0.f,0.f,0.f,0.f}; }
    #pragma unroll
    for (int ks = 0; ks < 4; ++ks) {
        int k = ks * 32 + kA;
        short8 w0 = *reinterpret_cast<const short8*>(aW1Ut + nc0 * EN + k);
        short8 w1 = *reinterpret_cast<const short8*>(aW1Ut + nc1 * EN + k);
        #pragma unroll
        for (int m = 0; m < 3; ++m) {
            short8 a = LDROW(sNg, 272, m * 16 + lr, k);
            a1[m][0] = MFMA(a, w0, a1[m][0]);
            a1[m][1] = MFMA(a, w1, a1[m][1]);
        }
    }
    #pragma unroll
    for (int m = 0; m < 3; ++m)
        #pragma unroll
        for (int nt = 0; nt < 2; ++nt) {
            int n = nt ? nc1 : nc0;
            #pragma unroll
            for (int r = 0; r < 4; ++r) {
                int row = m * 16 + lq * 4 + r;
                int g = (row >= TT) ? 1 : 0;
                float v = fmaxf(a1[m][nt][r] + sNp[g * EN + n], 0.f);
                *reinterpret_cast<short*>(reinterpret_cast<char*>(sH1) + row * 272 + n * 2)
                    = (short)f2b(v);
            }
        }
    __syncthreads();

    // h2 = relu(h1 @ aW2 + ab2); logits accumulated in-register
    f32x4 a2[3][2];
    #pragma unroll
    for (int m = 0; m < 3; ++m) { a2[m][0] = {0.f,0.f,0.f,0.f}; a2[m][1] = {0.f,0.f,0.f,0.f}; }
    #pragma unroll
    for (int ks = 0; ks < 4; ++ks) {
        int k = ks * 32 + kA;
        short8 w0 = *reinterpret_cast<const short8*>(aW2t + nc0 * EN + k);
        short8 w1 = *reinterpret_cast<const short8*>(aW2t + nc1 * EN + k);
        #pragma unroll
        for (int m = 0; m < 3; ++m) {
            short8 a = LDROW(sH1, 272, m * 16 + lr, k);
            a2[m][0] = MFMA(a, w0, a2[m][0]);
            a2[m][1] = MFMA(a, w1, a2[m][1]);
        }
    }
    {
        float b0v = ab2[nc0], b1v = ab2[nc1];
        float w3a = sW3[nc0], w3b = sW3[nc1];
        #pragma unroll
        for (int m = 0; m < 3; ++m) {
            float lp[4];
            #pragma unroll
            for (int r = 0; r < 4; ++r) {
                float v0 = fmaxf(a2[m][0][r] + b0v, 0.f);
                float v1 = fmaxf(a2[m][1][r] + b1v, 0.f);
                lp[r] = v0 * w3a + v1 * w3b;
            }
            #pragma unroll
            for (int r = 0; r < 4; ++r) {
                float v = lp[r];
                v += __shfl_xor(v, 1, 16);
                v += __shfl_xor(v, 2, 16);
                v += __shfl_xor(v, 4, 16);
                v += __shfl_xor(v, 8, 16);
                if (lr == 0) sLogP[wid][m * 16 + lq * 4 + r] = v;
            }
        }
    }
    __syncthreads();
    if (tid < 48)
        sLog[tid] = sLogP[0][tid] + sLogP[1][tid] + sLogP[2][tid] + sLogP[3][tid] + ab3[0];
    __syncthreads();

    // softmax over T=24, two groups in wave 0
    if (tid < 64) {
        int g = tid >> 5, tt = tid & 31;
        float v = (tt < TT) ? sLog[g * TT + tt] : -1e30f;
        float mx = v;
        #pragma unroll
        for (int d = 16; d > 0; d >>= 1) mx = fmaxf(mx, __shfl_xor(mx, d, 32));
        float p = (tt < TT) ? __expf(v - mx) : 0.f;
        float s = p;
        #pragma unroll
        for (int d = 16; d > 0; d >>= 1) s += __shfl_xor(s, d, 32);
        if (tt < TT) sAtt[g * TT + tt] = p / s;
    }
    __syncthreads();

    // agg + scatter
    {
        int g = tid >> 7, e = tid & 127;
        float a = 0.f;
        #pragma unroll
        for (int t = 0; t < TT; ++t) {
            unsigned short nv = *reinterpret_cast<const unsigned short*>(
                reinterpret_cast<const char*>(sNg) + (g * TT + t) * 272 + e * 2);
            a += sAtt[g * TT + t] * b2f(nv);
        }
        int node = sNode[g];
        if (owner[node] == b0 + g)
            out_embed[(size_t)node * EN + e] = a;
    }
}

extern "C" void kernel_launch(void* const* d_in, const int* in_sizes, int n_in,
                              void* d_out, int out_size, void* d_ws, size_t ws_size,
                              hipStream_t stream) {
    const int*   nodes     = (const int*)d_in[0];
    const int*   neigh_idx = (const int*)d_in[1];
    const float* u_weight  = (const float*)d_in[2];
    const float* i_weight  = (const float*)d_in[3];
    const float* uW  = (const float*)d_in[4];
    const float* ub  = (const float*)d_in[5];
    const float* iW  = (const float*)d_in[6];
    const float* ib  = (const float*)d_in[7];
    const float* aW1 = (const float*)d_in[8];
    const float* ab1 = (const float*)d_in[9];
    const float* aW2 = (const float*)d_in[10];
    const float* ab2 = (const float*)d_in[11];
    const float* aW3 = (const float*)d_in[12];
    const float* ab3 = (const float*)d_in[13];

    float* out_nf    = (float*)d_out;
    float* out_embed = out_nf + (size_t)BB * EN;

    char*  ws    = (char*)d_ws;
    short* wpack = (short*)(ws + WP_OFF);
    int*   owner = (int*)(ws + OWNER_OFF);
    short* ntab  = (short*)(ws + NTAB_OFF);
    float* npart = (float*)(ws + NPART_OFF);

    hipMemsetAsync(out_embed, 0, (size_t)NU * EN * sizeof(float), stream);
    hipMemsetAsync(owner, 0xFF, (size_t)NU * sizeof(int), stream);
    owner_kernel<<<(BB + 255) / 256, 256, 0, stream>>>(nodes, owner);
    pack_weights<<<(WPACK_SHORTS + 255) / 256, 256, 0, stream>>>(uW, iW, aW1, aW2, wpack);
    neighs_all_kernel<<<(NI + 63) / 64, 256, 0, stream>>>(i_weight, ib, wpack, ntab);
    nf_npart_kernel<<<BB / 64, 256, 0, stream>>>(nodes, u_weight, ub, ab1, wpack, out_nf, npart);
    attn_kernel<<<BB / 2, 256, 0, stream>>>(nodes, neigh_idx, ab2, aW3, ab3,
                                            wpack, ntab, npart, owner, out_embed);
}